// Round 1
// baseline (836.325 us; speedup 1.0000x reference)
//
#include <hip/hip_runtime.h>

// Problem constants (DepthwiseSeparableConv_11184094839306)
#define BB 16
#define CC 128
#define HH 128
#define WW 128
#define OO 256

// Fused depthwise-separable conv:
//   y[b,c,h,w] = sum_{i,j} col[c,i]*row[c,j]*x[b,c,h+i-1,w+j-1]   (pad=1)
//   out[b,o,h,w] = sum_c pw[o,c] * y[b,c,h,w]
//
// One block per (b,h) row. Phase 1: depthwise for all 128 channels of the row
// into LDS. Phase 2: 256x128 GEMM (K=128) with 8o x 8w register blocking,
// pw^T staged into LDS in two 64-channel halves.
__global__ __launch_bounds__(512, 1)
void dwsep_fused(const float* __restrict__ x,
                 const float* __restrict__ colk,
                 const float* __restrict__ rowk,
                 const float* __restrict__ pw,
                 float* __restrict__ out)
{
    __shared__ float ylds[CC][WW];        // 64 KiB: y[c][w] for this row
    __shared__ float pwT[64][OO + 4];     // 65 KiB: pw^T half, +4 pad breaks stride-256 bank conflicts

    const int tid = threadIdx.x;
    const int bh  = blockIdx.x;
    const int b   = bh >> 7;              // / 128
    const int h   = bh & 127;

    // ---------------- Phase 1: depthwise row into LDS ----------------
    {
        const int w  = tid & 127;         // lanes are w-consecutive -> coalesced x loads
        const int cg = tid >> 7;          // 0..3  (wave-uniform -> scalar weight loads)
        const bool hm = (h > 0);
        const bool hp = (h < HH - 1);
        const bool wm = (w > 0);
        const bool wp = (w < WW - 1);
        const size_t base_b = (size_t)b * CC * HH * WW;
        #pragma unroll 4
        for (int cc = 0; cc < 32; ++cc) {
            const int c = cg * 32 + cc;
            const float* xr = x + base_b + ((size_t)c * HH + h) * WW + w;
            const float c0 = colk[c * 3 + 0];
            const float c1 = colk[c * 3 + 1];
            const float c2 = colk[c * 3 + 2];
            const float r0 = rowk[c * 3 + 0];
            const float r1 = rowk[c * 3 + 1];
            const float r2 = rowk[c * 3 + 2];
            float acc;
            {   // center row (always valid)
                const float xm = wm ? xr[-1] : 0.0f;
                const float x0 = xr[0];
                const float xp = wp ? xr[1] : 0.0f;
                acc = c1 * (r0 * xm + r1 * x0 + r2 * xp);
            }
            if (hm) {
                const float* p = xr - WW;
                const float xm = wm ? p[-1] : 0.0f;
                const float x0 = p[0];
                const float xp = wp ? p[1] : 0.0f;
                acc += c0 * (r0 * xm + r1 * x0 + r2 * xp);
            }
            if (hp) {
                const float* p = xr + WW;
                const float xm = wm ? p[-1] : 0.0f;
                const float x0 = p[0];
                const float xp = wp ? p[1] : 0.0f;
                acc += c2 * (r0 * xm + r1 * x0 + r2 * xp);
            }
            ylds[c][w] = acc;
        }
    }

    // ---------------- Phase 2: GEMM out[o][w] = sum_c pw[o][c]*y[c][w] ----
    // Thread tile: 8 o x 8 w. 512 threads = 32 o-groups x 16 w-groups.
    // w-tile is split {wt*4..+3} U {64+wt*4..+3} so each ds_read_b128 has
    // consecutive lanes on consecutive 16B granules (conflict-free).
    const int wt = tid & 15;
    const int og = tid >> 4;              // 0..31 -> o = og*8 .. og*8+7

    float acc[8][8];
    #pragma unroll
    for (int k = 0; k < 8; ++k)
        #pragma unroll
        for (int j = 0; j < 8; ++j) acc[k][j] = 0.0f;

    for (int half = 0; half < 2; ++half) {
        __syncthreads();   // y written (first iter) / previous-half reads done (second iter)
        // Stage pwT[cl][o] = pw[o][half*64 + cl]; global reads coalesced in cl.
        #pragma unroll
        for (int i = 0; i < 32; ++i) {
            const int idx = i * 512 + tid;     // 0..16383
            const int o   = idx >> 6;          // wave-uniform
            const int cl  = idx & 63;          // = lane -> coalesced
            pwT[cl][o] = pw[o * CC + half * 64 + cl];
        }
        __syncthreads();
        const int cbase = half * 64;
        #pragma unroll 2
        for (int cl = 0; cl < 64; ++cl) {
            const float4 ya = *(const float4*)&ylds[cbase + cl][wt * 4];
            const float4 yb = *(const float4*)&ylds[cbase + cl][64 + wt * 4];
            const float4 pa = *(const float4*)&pwT[cl][og * 8];
            const float4 pb = *(const float4*)&pwT[cl][og * 8 + 4];
            const float yv[8] = {ya.x, ya.y, ya.z, ya.w, yb.x, yb.y, yb.z, yb.w};
            const float pv[8] = {pa.x, pa.y, pa.z, pa.w, pb.x, pb.y, pb.z, pb.w};
            #pragma unroll
            for (int k = 0; k < 8; ++k)
                #pragma unroll
                for (int j = 0; j < 8; ++j)
                    acc[k][j] += pv[k] * yv[j];
        }
    }

    // ---------------- Epilogue: coalesced float4 stores ----------------
    #pragma unroll
    for (int k = 0; k < 8; ++k) {
        const int o = og * 8 + k;
        float* op = out + (((size_t)b * OO + o) * HH + h) * WW;
        const float4 v0 = make_float4(acc[k][0], acc[k][1], acc[k][2], acc[k][3]);
        const float4 v1 = make_float4(acc[k][4], acc[k][5], acc[k][6], acc[k][7]);
        *(float4*)&op[wt * 4]       = v0;
        *(float4*)&op[64 + wt * 4]  = v1;
    }
}

extern "C" void kernel_launch(void* const* d_in, const int* in_sizes, int n_in,
                              void* d_out, int out_size, void* d_ws, size_t ws_size,
                              hipStream_t stream) {
    const float* x    = (const float*)d_in[0];   // (16,128,128,128)
    const float* colk = (const float*)d_in[1];   // (128,1,3,1)
    const float* rowk = (const float*)d_in[2];   // (128,1,1,3)
    const float* pw   = (const float*)d_in[3];   // (256,128)
    float* out = (float*)d_out;                  // (16,256,128,128)

    dim3 grid(BB * HH);   // 2048 blocks, one per (b,h)
    dim3 block(512);
    hipLaunchKernelGGL(dwsep_fused, grid, block, 0, stream, x, colk, rowk, pw, out);
}

// Round 2
// 611.872 us; speedup vs baseline: 1.3668x; 1.3668x over previous
//
#include <hip/hip_runtime.h>

// Problem: depthwise(3x3, rank-1) + pointwise(256x128) conv, fp32 in/out.
// B=16, C=128, H=W=128, OUT=256.
#define BB 16
#define CC 128
#define HH 128
#define WW 128
#define OO 256
#define RR 4               // h rows per block
#define HW (HH * WW)

typedef float f32x4 __attribute__((ext_vector_type(4)));
typedef short bf16x8 __attribute__((ext_vector_type(8)));

__device__ __forceinline__ unsigned short f2bf(float f) {
    unsigned int u = __float_as_uint(f);
    unsigned int r = (u + 0x7FFFu + ((u >> 16) & 1u)) >> 16;
    return (unsigned short)r;
}

// Per block: fixed b, rows h0..h0+RR-1.
//   phase1: depthwise row -> ybuf (bf16, transposed [w][c], XOR-swizzled 16B groups)
//   gemm:   out[o][w] = sum_c pw[o][c]*y[c][w] via mfma_f32_16x16x32_bf16
// A (pw) lives in registers per wave (block-invariant). Double-buffered rows,
// one barrier per row.
__global__ __launch_bounds__(512, 2)
void dwsep_mfma(const float* __restrict__ x,
                const float* __restrict__ colk,
                const float* __restrict__ rowk,
                const float* __restrict__ pw,
                float* __restrict__ out)
{
    // ybuf[buf][w][c'] bf16, pitch 128 (no pad; XOR swizzle on 8-elem groups).
    __shared__ __align__(16) unsigned short ybuf[2][WW][CC];   // 64 KiB

    const int tid  = threadIdx.x;
    const int lane = tid & 63;
    const int wave = tid >> 6;          // 0..7
    const int la   = lane & 15;         // MFMA n/m lane index
    const int qa   = lane >> 4;         // MFMA quad 0..3
    const int mg   = wave >> 1;         // o-group: o base = mg*64
    const int ng   = wave & 1;          // w-group: w base = ng*64

    const int blk = blockIdx.x;
    const int b   = blk >> 5;           // 16 b values
    const int h0  = (blk & 31) * RR;    // 32 strips of RR rows

    // ---------- A fragments: pw -> bf16 registers (once per block) ----------
    // A[m=la][k=qa*8+j] ; afrag[ot][ks] covers o = mg*64+ot*16+la, c = ks*32+qa*8+j
    bf16x8 afrag[4][4];
    {
        #pragma unroll
        for (int ot = 0; ot < 4; ++ot) {
            const float* prow = pw + (size_t)(mg * 64 + ot * 16 + la) * CC;
            #pragma unroll
            for (int ks = 0; ks < 4; ++ks) {
                const int c0 = ks * 32 + qa * 8;
                const float4 f0 = *(const float4*)(prow + c0);
                const float4 f1 = *(const float4*)(prow + c0 + 4);
                bf16x8 a;
                a[0] = (short)f2bf(f0.x); a[1] = (short)f2bf(f0.y);
                a[2] = (short)f2bf(f0.z); a[3] = (short)f2bf(f0.w);
                a[4] = (short)f2bf(f1.x); a[5] = (short)f2bf(f1.y);
                a[6] = (short)f2bf(f1.z); a[7] = (short)f2bf(f1.w);
                afrag[ot][ks] = a;
            }
        }
    }

    // ---------- phase 1: depthwise one row -> ybuf[buf] ----------
    const int wph = tid & 127;          // w position (lane-contiguous -> coalesced x)
    const int cg  = tid >> 7;           // 0..3, wave-uniform -> scalar weight loads
    const size_t base_b = (size_t)b * CC * HW;

    auto phase1 = [&](int hrow, int buf) {
        const bool hm  = (hrow > 0);
        const bool hp  = (hrow < HH - 1);
        const bool wmv = (wph > 0);
        const bool wpv = (wph < WW - 1);
        #pragma unroll 2
        for (int ci = 0; ci < 16; ++ci) {           // channel pairs
            unsigned int pack = 0;
            #pragma unroll
            for (int t = 0; t < 2; ++t) {
                const int c = cg * 32 + ci * 2 + t;
                const float* xr = x + base_b + ((size_t)c * HH + hrow) * WW + wph;
                const float c0k = colk[c * 3 + 0];
                const float c1k = colk[c * 3 + 1];
                const float c2k = colk[c * 3 + 2];
                const float r0k = rowk[c * 3 + 0];
                const float r1k = rowk[c * 3 + 1];
                const float r2k = rowk[c * 3 + 2];
                float acc;
                {   // center x-row always valid
                    const float xm = wmv ? xr[-1] : 0.0f;
                    const float xc = xr[0];
                    const float xp = wpv ? xr[1] : 0.0f;
                    acc = c1k * (r0k * xm + r1k * xc + r2k * xp);
                }
                if (hm) {
                    const float* p = xr - WW;
                    const float xm = wmv ? p[-1] : 0.0f;
                    const float xc = p[0];
                    const float xp = wpv ? p[1] : 0.0f;
                    acc += c0k * (r0k * xm + r1k * xc + r2k * xp);
                }
                if (hp) {
                    const float* p = xr + WW;
                    const float xm = wmv ? p[-1] : 0.0f;
                    const float xc = p[0];
                    const float xp = wpv ? p[1] : 0.0f;
                    acc += c2k * (r0k * xm + r1k * xc + r2k * xp);
                }
                pack |= (unsigned int)f2bf(acc) << (16 * t);
            }
            // transposed store y[w][c], swizzle 16B group: g' = g ^ (w&15)
            const int c = cg * 32 + ci * 2;
            const int csw = (((c >> 3) ^ (wph & 15)) << 3) | (c & 7);
            *(unsigned int*)&ybuf[buf][wph][csw] = pack;
        }
    };

    // ---------- gemm: one row out[o][w] += pw * y ----------
    auto gemm = [&](int hrow, int buf) {
        f32x4 acc[4][4];
        #pragma unroll
        for (int ot = 0; ot < 4; ++ot)
            #pragma unroll
            for (int wt = 0; wt < 4; ++wt)
                acc[ot][wt] = (f32x4){0.f, 0.f, 0.f, 0.f};

        #pragma unroll
        for (int ks = 0; ks < 4; ++ks) {
            // B[k=qa*8+j][n=la]: 8 c-contiguous bf16 at y[w][c0], swizzled group
            bf16x8 bfr[4];
            const int g = ks * 4 + qa;              // c group index c0>>3
            #pragma unroll
            for (int wt = 0; wt < 4; ++wt) {
                const int w = ng * 64 + wt * 16 + la;
                const int csw = (g ^ la) << 3;      // w&15 == la
                bfr[wt] = *(const bf16x8*)&ybuf[buf][w][csw];
            }
            #pragma unroll
            for (int wt = 0; wt < 4; ++wt)
                #pragma unroll
                for (int ot = 0; ot < 4; ++ot)
                    acc[ot][wt] = __builtin_amdgcn_mfma_f32_16x16x32_bf16(
                        afrag[ot][ks], bfr[wt], acc[ot][wt], 0, 0, 0);
        }

        // D[row = qa*4 + r][col = la]; store 4 o-rows per fragment
        const size_t outb = (size_t)b * OO * HW + (size_t)hrow * WW;
        #pragma unroll
        for (int ot = 0; ot < 4; ++ot) {
            const int o = mg * 64 + ot * 16 + qa * 4;
            #pragma unroll
            for (int wt = 0; wt < 4; ++wt) {
                const int w = ng * 64 + wt * 16 + la;
                float* op = out + outb + (size_t)o * HW + w;
                op[0 * HW] = acc[ot][wt][0];
                op[1 * HW] = acc[ot][wt][1];
                op[2 * HW] = acc[ot][wt][2];
                op[3 * HW] = acc[ot][wt][3];
            }
        }
    };

    // ---------- main loop: 1 barrier per row, double-buffered ----------
    phase1(h0, 0);
    for (int r = 0; r < RR; ++r) {
        __syncthreads();
        gemm(h0 + r, r & 1);
        if (r + 1 < RR) phase1(h0 + r + 1, (r + 1) & 1);
    }
}

extern "C" void kernel_launch(void* const* d_in, const int* in_sizes, int n_in,
                              void* d_out, int out_size, void* d_ws, size_t ws_size,
                              hipStream_t stream) {
    const float* x    = (const float*)d_in[0];   // (16,128,128,128)
    const float* colk = (const float*)d_in[1];   // (128,1,3,1)
    const float* rowk = (const float*)d_in[2];   // (128,1,1,3)
    const float* pw   = (const float*)d_in[3];   // (256,128)
    float* out = (float*)d_out;                  // (16,256,128,128)

    dim3 grid(BB * (HH / RR));   // 512 blocks: (b, h-strip)
    dim3 block(512);
    hipLaunchKernelGGL(dwsep_mfma, grid, block, 0, stream, x, colk, rowk, pw, out);
}